// Round 1
// baseline (1053.112 us; speedup 1.0000x reference)
//
#include <hip/hip_runtime.h>

typedef unsigned short u16;
typedef unsigned int   u32;
typedef unsigned long long u64;
typedef __attribute__((ext_vector_type(8))) __bf16 bf16x8;
typedef __attribute__((ext_vector_type(4))) float  f32x4;

#define TOK 8192
#define DIM 1024
#define NE  16
#define NF  4096
#define CAP 512

// ---------- helpers ----------
__device__ __forceinline__ u16 f2bf(float f) {
    u32 u = __float_as_uint(f);
    u32 r = (u + 0x7FFFu + ((u >> 16) & 1u)) >> 16;   // RNE
    return (u16)r;
}

__device__ __forceinline__ float gelu_tanh(float x) {
    float u = 0.7978845608028654f * (x + 0.044715f * x * x * x);
    float t = __expf(-2.f * fabsf(u));
    float th = (1.f - t) / (1.f + t);
    th = (u < 0.f) ? -th : th;
    return 0.5f * x * (1.f + th);
}

__device__ __forceinline__ void gld16(const void* g, void* l) {
    __builtin_amdgcn_global_load_lds(
        (const __attribute__((address_space(1))) void*)g,
        (__attribute__((address_space(3))) void*)l, 16, 0, 0);
}

// ---------- small kernels ----------
__global__ void moe_init(float* me_sums) {
    if (threadIdx.x < NE) me_sums[threadIdx.x] = 0.f;
}

__global__ void moe_wgT(const float* __restrict__ wg, float* __restrict__ wgT) {
    int i = blockIdx.x * 256 + threadIdx.x;     // 16384 elements
    int d = i >> 4, e = i & 15;
    wgT[(size_t)e * DIM + d] = wg[i];
}

// one thread per (token, expert); 256 thr = 16 tokens x 16 experts
__global__ void moe_gate(const float* __restrict__ x, const float* __restrict__ wgT,
                         int* __restrict__ eidx, float* __restrict__ gp,
                         float* __restrict__ me_sums) {
    __shared__ float lme[NE];
    const int tid = threadIdx.x;
    if (tid < NE) lme[tid] = 0.f;
    __syncthreads();
    const int tok = blockIdx.x * 16 + (tid >> 4);
    const int e   = tid & 15;
    const float4* xp = (const float4*)(x + (size_t)tok * DIM);
    const float4* wp = (const float4*)(wgT + (size_t)e * DIM);
    float acc = 0.f;
#pragma unroll 4
    for (int i = 0; i < DIM / 4; ++i) {
        float4 a = xp[i], b = wp[i];
        acc = fmaf(a.x, b.x, acc); acc = fmaf(a.y, b.y, acc);
        acc = fmaf(a.z, b.z, acc); acc = fmaf(a.w, b.w, acc);
    }
    // softmax across the 16-lane expert group
    float mx = acc;
    for (int off = 8; off; off >>= 1) mx = fmaxf(mx, __shfl_xor(mx, off, 16));
    float ex = __expf(acc - mx);
    float sum = ex;
    for (int off = 8; off; off >>= 1) sum += __shfl_xor(sum, off, 16);
    float p = ex / sum;
    atomicAdd(&lme[e], p);
    // argmax (first index on ties, matching jnp.argmax)
    float bv = acc; int bi = e;
    for (int off = 8; off; off >>= 1) {
        float ov = __shfl_xor(bv, off, 16);
        int   oi = __shfl_xor(bi, off, 16);
        if (ov > bv || (ov == bv && oi < bi)) { bv = ov; bi = oi; }
    }
    float pw = __shfl(p, bi, 16);
    if (e == 0) { eidx[tok] = bi; gp[tok] = pw; }
    __syncthreads();
    if (tid < NE) atomicAdd(&me_sums[tid], lme[tid]);
}

// single block, 1024 threads: ordered cumsum slot assignment + counts + l_aux
__global__ void moe_scan(const int* __restrict__ eidx, const float* __restrict__ me_sums,
                         int* __restrict__ slot, int* __restrict__ tos,
                         float* __restrict__ tail /* d_out + TOK*DIM */) {
    __shared__ int wcnt[16][16];
    __shared__ int base[16];
    const int tid = threadIdx.x, wid = tid >> 6, lane = tid & 63;
    if (tid < 16) base[tid] = 0;
    for (int i = tid; i < NE * CAP; i += 1024) tos[i] = -1;
    __syncthreads();
    const u64 below = ((u64)1 << lane) - 1;
    for (int chunk = 0; chunk < TOK / 1024; ++chunk) {
        int t = chunk * 1024 + tid;
        int e = eidx[t];
        int rank = 0;
#pragma unroll
        for (int ex = 0; ex < 16; ++ex) {
            u64 m = __ballot(e == ex);
            if (e == ex)    rank = __popcll(m & below);
            if (lane == ex) wcnt[wid][ex] = __popcll(m);
        }
        __syncthreads();
        int pre = base[e];
        for (int w = 0; w < wid; ++w) pre += wcnt[w][e];
        int s = pre + rank;
        slot[t] = s;
        if (s < CAP) tos[e * CAP + s] = t;
        __syncthreads();
        if (tid < 16) {
            int tot = 0;
            for (int w = 0; w < 16; ++w) tot += wcnt[w][tid];
            base[tid] += tot;
        }
        __syncthreads();
    }
    if (tid == 0) {
        float laux = 0.f;
        for (int e2 = 0; e2 < 16; ++e2) {
            float me = me_sums[e2] / (float)TOK;
            float ce = (float)base[e2] / (float)TOK;
            laux += me * ce;
        }
        tail[0] = laux * (float)NE;
    }
    if (tid < 16) tail[1 + tid] = (float)base[tid];
}

// one block per slot row: gather x[token] -> bf16 Xg[slot]
__global__ void moe_gather(const float* __restrict__ x, const int* __restrict__ tos,
                           u16* __restrict__ Xg) {
    const int s = blockIdx.x, tid = threadIdx.x;
    const int t = tos[s];
    float4 v = make_float4(0.f, 0.f, 0.f, 0.f);
    if (t >= 0) v = *(const float4*)(x + (size_t)t * DIM + tid * 4);
    u32 lo = (u32)f2bf(v.x) | ((u32)f2bf(v.y) << 16);
    u32 hi = (u32)f2bf(v.z) | ((u32)f2bf(v.w) << 16);
    *(uint2*)(Xg + (size_t)s * DIM + tid * 4) = make_uint2(lo, hi);
}

__global__ void moe_zero_dropped(const int* __restrict__ slot, float* __restrict__ out) {
    const int t = blockIdx.x;
    if (slot[t] < CAP) return;
    *(float4*)(out + (size_t)t * DIM + threadIdx.x * 4) = make_float4(0.f, 0.f, 0.f, 0.f);
}

// transpose+convert: src [E][R][C] f32 -> dst [E][C][R] bf16 (64x64 tiles)
__global__ void moe_convT(const float* __restrict__ src, u16* __restrict__ dst,
                          int R, int C) {
    __shared__ float tile[64][65];
    int b = blockIdx.x;
    const int tilesC = C >> 6, tilesR = R >> 6;
    int tc = b % tilesC; b /= tilesC;
    int tr = b % tilesR; int e = b / tilesR;
    const float* S = src + ((size_t)e * R + tr * 64) * C + tc * 64;
    const int tid = threadIdx.x;
    const int rr = tid >> 4, cc = (tid & 15) * 4;
#pragma unroll
    for (int i = 0; i < 4; ++i) {
        float4 v = *(const float4*)(S + (size_t)(rr + i * 16) * C + cc);
        tile[rr + i * 16][cc + 0] = v.x; tile[rr + i * 16][cc + 1] = v.y;
        tile[rr + i * 16][cc + 2] = v.z; tile[rr + i * 16][cc + 3] = v.w;
    }
    __syncthreads();
    const int c = tid >> 2, r0 = (tid & 3) * 16;
    u16 tmp[16];
#pragma unroll
    for (int k = 0; k < 16; ++k) tmp[k] = f2bf(tile[r0 + k][c]);
    u16* D = dst + ((size_t)e * C + tc * 64 + c) * R + tr * 64 + r0;
    uint4 w0 = make_uint4((u32)tmp[0] | ((u32)tmp[1] << 16), (u32)tmp[2] | ((u32)tmp[3] << 16),
                          (u32)tmp[4] | ((u32)tmp[5] << 16), (u32)tmp[6] | ((u32)tmp[7] << 16));
    uint4 w1 = make_uint4((u32)tmp[8] | ((u32)tmp[9] << 16), (u32)tmp[10] | ((u32)tmp[11] << 16),
                          (u32)tmp[12] | ((u32)tmp[13] << 16), (u32)tmp[14] | ((u32)tmp[15] << 16));
    *(uint4*)(D) = w0;
    *(uint4*)(D + 8) = w1;
}

// ---------- GEMM1: H = gelu(Xg @ w1 + b1), bf16 out ----------
// grid (4, NF/128, NE); A=Xg [8192][1024] bf16, B=W1t [E][NF][DIM] bf16 (n-major)
__global__ __launch_bounds__(256) void moe_gemm1(const u16* __restrict__ Xg,
                                                 const u16* __restrict__ W1t,
                                                 const float* __restrict__ b1,
                                                 u16* __restrict__ H) {
    __shared__ alignas(16) u16 Als[128 * 32];
    __shared__ alignas(16) u16 Bls[128 * 32];
    const int tid = threadIdx.x, wave = tid >> 6, lane = tid & 63;
    const int e  = blockIdx.z;
    const int bm = blockIdx.z * 4 + blockIdx.x;
    const int bn = blockIdx.y;
    const u16* aSrc = Xg + (size_t)(bm * 128 + wave * 32 + (lane >> 2)) * DIM + (lane & 3) * 8;
    const u16* bSrc = W1t + (size_t)e * NF * DIM
                    + (size_t)(bn * 128 + wave * 32 + (lane >> 2)) * DIM + (lane & 3) * 8;
    u16* aDst = Als + wave * 1024;
    u16* bDst = Bls + wave * 1024;
    f32x4 acc[4][4] = {};
    const int wm = wave & 1, wn = wave >> 1;
    const int fr = lane & 15, fq = lane >> 4;
    for (int k0 = 0; k0 < DIM; k0 += 32) {
        gld16(aSrc, aDst);
        gld16(aSrc + 16 * DIM, aDst + 512);
        gld16(bSrc, bDst);
        gld16(bSrc + 16 * DIM, bDst + 512);
        aSrc += 32; bSrc += 32;
        __syncthreads();
        bf16x8 aF[4], bF[4];
#pragma unroll
        for (int i = 0; i < 4; ++i)
            aF[i] = *(const bf16x8*)(const void*)(Als + (wm * 64 + i * 16 + fr) * 32 + fq * 8);
#pragma unroll
        for (int j = 0; j < 4; ++j)
            bF[j] = *(const bf16x8*)(const void*)(Bls + (wn * 64 + j * 16 + fr) * 32 + fq * 8);
#pragma unroll
        for (int i = 0; i < 4; ++i)
#pragma unroll
            for (int j = 0; j < 4; ++j)
                acc[i][j] = __builtin_amdgcn_mfma_f32_16x16x32_bf16(aF[i], bF[j], acc[i][j], 0, 0, 0);
        __syncthreads();
    }
    const int mBase = bm * 128 + wm * 64;
    const int nBase = bn * 128 + wn * 64;
#pragma unroll
    for (int j = 0; j < 4; ++j) {
        const int f = nBase + j * 16 + fr;
        const float bias = b1[e * NF + f];
#pragma unroll
        for (int i = 0; i < 4; ++i) {
            const int m0 = mBase + i * 16 + fq * 4;
#pragma unroll
            for (int r = 0; r < 4; ++r) {
                float v = acc[i][j][r] + bias;
                H[(size_t)(m0 + r) * NF + f] = f2bf(gelu_tanh(v));
            }
        }
    }
}

// ---------- GEMM2: out[token] = gate * (H @ w2 + b2), scattered ----------
// grid (4, DIM/128, NE); A=H [8192][4096] bf16, B=W2t [E][DIM][NF] bf16 (n-major)
__global__ __launch_bounds__(256) void moe_gemm2(const u16* __restrict__ H,
                                                 const u16* __restrict__ W2t,
                                                 const float* __restrict__ b2,
                                                 const int* __restrict__ tos,
                                                 const float* __restrict__ gp,
                                                 float* __restrict__ out) {
    __shared__ alignas(16) u16 Als[128 * 32];
    __shared__ alignas(16) u16 Bls[128 * 32];
    const int tid = threadIdx.x, wave = tid >> 6, lane = tid & 63;
    const int e  = blockIdx.z;
    const int bm = blockIdx.z * 4 + blockIdx.x;
    const int bn = blockIdx.y;
    const u16* aSrc = H + (size_t)(bm * 128 + wave * 32 + (lane >> 2)) * NF + (lane & 3) * 8;
    const u16* bSrc = W2t + (size_t)e * DIM * NF
                    + (size_t)(bn * 128 + wave * 32 + (lane >> 2)) * NF + (lane & 3) * 8;
    u16* aDst = Als + wave * 1024;
    u16* bDst = Bls + wave * 1024;
    f32x4 acc[4][4] = {};
    const int wm = wave & 1, wn = wave >> 1;
    const int fr = lane & 15, fq = lane >> 4;
    for (int k0 = 0; k0 < NF; k0 += 32) {
        gld16(aSrc, aDst);
        gld16(aSrc + 16 * NF, aDst + 512);
        gld16(bSrc, bDst);
        gld16(bSrc + 16 * NF, bDst + 512);
        aSrc += 32; bSrc += 32;
        __syncthreads();
        bf16x8 aF[4], bF[4];
#pragma unroll
        for (int i = 0; i < 4; ++i)
            aF[i] = *(const bf16x8*)(const void*)(Als + (wm * 64 + i * 16 + fr) * 32 + fq * 8);
#pragma unroll
        for (int j = 0; j < 4; ++j)
            bF[j] = *(const bf16x8*)(const void*)(Bls + (wn * 64 + j * 16 + fr) * 32 + fq * 8);
#pragma unroll
        for (int i = 0; i < 4; ++i)
#pragma unroll
            for (int j = 0; j < 4; ++j)
                acc[i][j] = __builtin_amdgcn_mfma_f32_16x16x32_bf16(aF[i], bF[j], acc[i][j], 0, 0, 0);
        __syncthreads();
    }
    const int mBase = bm * 128 + wm * 64;
    const int nBase = bn * 128 + wn * 64;
#pragma unroll
    for (int i = 0; i < 4; ++i) {
#pragma unroll
        for (int r = 0; r < 4; ++r) {
            const int m = mBase + i * 16 + fq * 4 + r;
            const int t = tos[m];
            if (t < 0) continue;
            const float g = gp[t];
#pragma unroll
            for (int j = 0; j < 4; ++j) {
                const int d = nBase + j * 16 + fr;
                out[(size_t)t * DIM + d] = g * (acc[i][j][r] + b2[e * DIM + d]);
            }
        }
    }
}

// ---------- launch ----------
extern "C" void kernel_launch(void* const* d_in, const int* in_sizes, int n_in,
                              void* d_out, int out_size, void* d_ws, size_t ws_size,
                              hipStream_t stream) {
    const float* x  = (const float*)d_in[0];
    const float* wg = (const float*)d_in[1];
    const float* w1 = (const float*)d_in[2];
    const float* b1 = (const float*)d_in[3];
    const float* w2 = (const float*)d_in[4];
    const float* b2 = (const float*)d_in[5];
    float* out = (float*)d_out;

    char* ws = (char*)d_ws;
    const size_t WBF_OFF = 0;                                   // 134,217,728 B (shared by w1/w2 bf16)
    const size_t XG_OFF  = WBF_OFF + (size_t)NE * NF * DIM * 2; // 16,777,216 B
    const size_t H_OFF   = XG_OFF + (size_t)TOK * DIM * 2;      // 67,108,864 B
    const size_t SM_OFF  = H_OFF + (size_t)TOK * NF * 2;
    u16* Wbf = (u16*)(ws + WBF_OFF);
    u16* Xg  = (u16*)(ws + XG_OFF);
    u16* H   = (u16*)(ws + H_OFF);
    int*   eidx = (int*)(ws + SM_OFF);                 // 32 KB
    float* gp   = (float*)(ws + SM_OFF + 32768);       // 32 KB
    int*   slot = (int*)(ws + SM_OFF + 65536);         // 32 KB
    int*   tos  = (int*)(ws + SM_OFF + 98304);         // 32 KB
    float* me   = (float*)(ws + SM_OFF + 131072);      // 64 B
    float* wgT  = (float*)(ws + SM_OFF + 131072 + 128);// 64 KB (16B aligned)

    float* tail = out + (size_t)TOK * DIM;             // [l_aux, exp_counts x16]

    moe_init<<<1, 64, 0, stream>>>(me);
    moe_wgT<<<64, 256, 0, stream>>>(wg, wgT);
    moe_gate<<<TOK / 16, 256, 0, stream>>>(x, wgT, eidx, gp, me);
    moe_scan<<<1, 1024, 0, stream>>>(eidx, me, slot, tos, tail);
    moe_gather<<<NE * CAP, 256, 0, stream>>>(x, tos, Xg);
    moe_zero_dropped<<<TOK, 256, 0, stream>>>(slot, out);
    moe_convT<<<NE * (DIM / 64) * (NF / 64), 256, 0, stream>>>(w1, Wbf, DIM, NF);
    moe_gemm1<<<dim3(4, NF / 128, NE), 256, 0, stream>>>(Xg, Wbf, b1, H);
    moe_convT<<<NE * (NF / 64) * (DIM / 64), 256, 0, stream>>>(w2, Wbf, NF, DIM);
    moe_gemm2<<<dim3(4, DIM / 128, NE), 256, 0, stream>>>(H, Wbf, b2, tos, gp, out);
}

// Round 2
// 944.130 us; speedup vs baseline: 1.1154x; 1.1154x over previous
//
#include <hip/hip_runtime.h>

typedef unsigned short u16;
typedef unsigned int   u32;
typedef unsigned long long u64;
typedef __attribute__((ext_vector_type(8))) __bf16 bf16x8;
typedef __attribute__((ext_vector_type(4))) float  f32x4;

#define TOK 8192
#define DIM 1024
#define NE  16
#define NF  4096
#define CAP 512

// ---------- helpers ----------
__device__ __forceinline__ u16 f2bf(float f) {
    u32 u = __float_as_uint(f);
    u32 r = (u + 0x7FFFu + ((u >> 16) & 1u)) >> 16;   // RNE
    return (u16)r;
}

__device__ __forceinline__ float gelu_tanh(float x) {
    float u = 0.7978845608028654f * (x + 0.044715f * x * x * x);
    float t = __expf(-2.f * fabsf(u));
    float th = (1.f - t) / (1.f + t);
    th = (u < 0.f) ? -th : th;
    return 0.5f * x * (1.f + th);
}

__device__ __forceinline__ void gld16(const void* g, void* l) {
    __builtin_amdgcn_global_load_lds(
        (const __attribute__((address_space(1))) void*)g,
        (__attribute__((address_space(3))) void*)l, 16, 0, 0);
}

// ---------- small kernels ----------
__global__ void moe_init(float* me_sums) {
    if (threadIdx.x < NE) me_sums[threadIdx.x] = 0.f;
}

__global__ void moe_wgT(const float* __restrict__ wg, float* __restrict__ wgT) {
    int i = blockIdx.x * 256 + threadIdx.x;     // 16384 elements
    int d = i >> 4, e = i & 15;
    wgT[(size_t)e * DIM + d] = wg[i];
}

// one thread per (token, expert); 256 thr = 16 tokens x 16 experts
__global__ void moe_gate(const float* __restrict__ x, const float* __restrict__ wgT,
                         int* __restrict__ eidx, float* __restrict__ gp,
                         float* __restrict__ me_sums) {
    __shared__ float lme[NE];
    const int tid = threadIdx.x;
    if (tid < NE) lme[tid] = 0.f;
    __syncthreads();
    const int tok = blockIdx.x * 16 + (tid >> 4);
    const int e   = tid & 15;
    const float4* xp = (const float4*)(x + (size_t)tok * DIM);
    const float4* wp = (const float4*)(wgT + (size_t)e * DIM);
    float acc = 0.f;
#pragma unroll 4
    for (int i = 0; i < DIM / 4; ++i) {
        float4 a = xp[i], b = wp[i];
        acc = fmaf(a.x, b.x, acc); acc = fmaf(a.y, b.y, acc);
        acc = fmaf(a.z, b.z, acc); acc = fmaf(a.w, b.w, acc);
    }
    // softmax across the 16-lane expert group
    float mx = acc;
    for (int off = 8; off; off >>= 1) mx = fmaxf(mx, __shfl_xor(mx, off, 16));
    float ex = __expf(acc - mx);
    float sum = ex;
    for (int off = 8; off; off >>= 1) sum += __shfl_xor(sum, off, 16);
    float p = ex / sum;
    atomicAdd(&lme[e], p);
    // argmax (first index on ties, matching jnp.argmax)
    float bv = acc; int bi = e;
    for (int off = 8; off; off >>= 1) {
        float ov = __shfl_xor(bv, off, 16);
        int   oi = __shfl_xor(bi, off, 16);
        if (ov > bv || (ov == bv && oi < bi)) { bv = ov; bi = oi; }
    }
    float pw = __shfl(p, bi, 16);
    if (e == 0) { eidx[tok] = bi; gp[tok] = pw; }
    __syncthreads();
    if (tid < NE) atomicAdd(&me_sums[tid], lme[tid]);
}

// single block, 1024 threads: ordered cumsum slot assignment + counts + l_aux
__global__ void moe_scan(const int* __restrict__ eidx, const float* __restrict__ me_sums,
                         int* __restrict__ slot, int* __restrict__ tos,
                         float* __restrict__ tail /* d_out + TOK*DIM */) {
    __shared__ int wcnt[16][16];
    __shared__ int base[16];
    const int tid = threadIdx.x, wid = tid >> 6, lane = tid & 63;
    if (tid < 16) base[tid] = 0;
    for (int i = tid; i < NE * CAP; i += 1024) tos[i] = -1;
    __syncthreads();
    const u64 below = ((u64)1 << lane) - 1;
    for (int chunk = 0; chunk < TOK / 1024; ++chunk) {
        int t = chunk * 1024 + tid;
        int e = eidx[t];
        int rank = 0;
#pragma unroll
        for (int ex = 0; ex < 16; ++ex) {
            u64 m = __ballot(e == ex);
            if (e == ex)    rank = __popcll(m & below);
            if (lane == ex) wcnt[wid][ex] = __popcll(m);
        }
        __syncthreads();
        int pre = base[e];
        for (int w = 0; w < wid; ++w) pre += wcnt[w][e];
        int s = pre + rank;
        slot[t] = s;
        if (s < CAP) tos[e * CAP + s] = t;
        __syncthreads();
        if (tid < 16) {
            int tot = 0;
            for (int w = 0; w < 16; ++w) tot += wcnt[w][tid];
            base[tid] += tot;
        }
        __syncthreads();
    }
    if (tid == 0) {
        float laux = 0.f;
        for (int e2 = 0; e2 < 16; ++e2) {
            float me = me_sums[e2] / (float)TOK;
            float ce = (float)base[e2] / (float)TOK;
            laux += me * ce;
        }
        tail[0] = laux * (float)NE;
    }
    if (tid < 16) tail[1 + tid] = (float)base[tid];
}

// one block per slot row: gather x[token] -> bf16 Xg[slot]
__global__ void moe_gather(const float* __restrict__ x, const int* __restrict__ tos,
                           u16* __restrict__ Xg) {
    const int s = blockIdx.x, tid = threadIdx.x;
    const int t = tos[s];
    float4 v = make_float4(0.f, 0.f, 0.f, 0.f);
    if (t >= 0) v = *(const float4*)(x + (size_t)t * DIM + tid * 4);
    u32 lo = (u32)f2bf(v.x) | ((u32)f2bf(v.y) << 16);
    u32 hi = (u32)f2bf(v.z) | ((u32)f2bf(v.w) << 16);
    *(uint2*)(Xg + (size_t)s * DIM + tid * 4) = make_uint2(lo, hi);
}

__global__ void moe_zero_dropped(const int* __restrict__ slot, float* __restrict__ out) {
    const int t = blockIdx.x;
    if (slot[t] < CAP) return;
    *(float4*)(out + (size_t)t * DIM + threadIdx.x * 4) = make_float4(0.f, 0.f, 0.f, 0.f);
}

// transpose+convert: src [E][R][C] f32 -> dst [E][C][R] bf16 (64x64 tiles)
__global__ void moe_convT(const float* __restrict__ src, u16* __restrict__ dst,
                          int R, int C) {
    __shared__ float tile[64][65];
    int b = blockIdx.x;
    const int tilesC = C >> 6, tilesR = R >> 6;
    int tc = b % tilesC; b /= tilesC;
    int tr = b % tilesR; int e = b / tilesR;
    const float* S = src + ((size_t)e * R + tr * 64) * C + tc * 64;
    const int tid = threadIdx.x;
    const int rr = tid >> 4, cc = (tid & 15) * 4;
#pragma unroll
    for (int i = 0; i < 4; ++i) {
        float4 v = *(const float4*)(S + (size_t)(rr + i * 16) * C + cc);
        tile[rr + i * 16][cc + 0] = v.x; tile[rr + i * 16][cc + 1] = v.y;
        tile[rr + i * 16][cc + 2] = v.z; tile[rr + i * 16][cc + 3] = v.w;
    }
    __syncthreads();
    const int c = tid >> 2, r0 = (tid & 3) * 16;
    u16 tmp[16];
#pragma unroll
    for (int k = 0; k < 16; ++k) tmp[k] = f2bf(tile[r0 + k][c]);
    u16* D = dst + ((size_t)e * C + tc * 64 + c) * R + tr * 64 + r0;
    uint4 w0 = make_uint4((u32)tmp[0] | ((u32)tmp[1] << 16), (u32)tmp[2] | ((u32)tmp[3] << 16),
                          (u32)tmp[4] | ((u32)tmp[5] << 16), (u32)tmp[6] | ((u32)tmp[7] << 16));
    uint4 w1 = make_uint4((u32)tmp[8] | ((u32)tmp[9] << 16), (u32)tmp[10] | ((u32)tmp[11] << 16),
                          (u32)tmp[12] | ((u32)tmp[13] << 16), (u32)tmp[14] | ((u32)tmp[15] << 16));
    *(uint4*)(D) = w0;
    *(uint4*)(D + 8) = w1;
}

// ---------- GEMM1: H = gelu(Xg @ w1 + b1), bf16 out ----------
// grid (NF/128, 4, NE); x=bn so bm-blocks sharing a B-tile are flat-stride-gridX
// apart (same XCD mod 8). 128x128 tile, BK=32, double-buffered, XOR-swizzled LDS.
__global__ __launch_bounds__(256) void moe_gemm1(const u16* __restrict__ Xg,
                                                 const u16* __restrict__ W1t,
                                                 const float* __restrict__ b1,
                                                 u16* __restrict__ H) {
    __shared__ alignas(16) u16 Als[2][4096];
    __shared__ alignas(16) u16 Bls[2][4096];
    const int tid = threadIdx.x, wave = tid >> 6, lane = tid & 63;
    const int e  = blockIdx.z;
    const int bm = e * 4 + blockIdx.y;
    const int bn = blockIdx.x;
    const int r4  = lane >> 2;
    const int gch = (lane & 3) ^ ((lane >> 3) & 3);   // swizzled chunk this lane fetches
    const u16* aS = Xg + (size_t)(bm * 128 + wave * 32 + r4) * DIM + gch * 8;
    const u16* bS = W1t + (size_t)e * NF * DIM
                  + (size_t)(bn * 128 + wave * 32 + r4) * DIM + gch * 8;
    u16* aD0 = &Als[0][wave * 1024]; u16* aD1 = &Als[1][wave * 1024];
    u16* bD0 = &Bls[0][wave * 1024]; u16* bD1 = &Bls[1][wave * 1024];
    f32x4 acc[4][4] = {};
    const int wm = wave & 1, wn = wave >> 1;
    const int fr = lane & 15, fq = lane >> 4;
    const int rdoff = fr * 32 + (fq ^ ((fr >> 1) & 3)) * 8;   // swizzled read offset

#define STAGE1(AD, BD, K) do { \
        gld16(aS + (K), AD); gld16(aS + (K) + 16 * DIM, (AD) + 512); \
        gld16(bS + (K), BD); gld16(bS + (K) + 16 * DIM, (BD) + 512); } while (0)
#define COMP1(AB, BB) do { \
        bf16x8 aF[4], bF[4]; \
        _Pragma("unroll") for (int i = 0; i < 4; ++i) \
            aF[i] = *(const bf16x8*)(const void*)((AB) + (wm * 64 + i * 16) * 32 + rdoff); \
        _Pragma("unroll") for (int j = 0; j < 4; ++j) \
            bF[j] = *(const bf16x8*)(const void*)((BB) + (wn * 64 + j * 16) * 32 + rdoff); \
        _Pragma("unroll") for (int i = 0; i < 4; ++i) \
        _Pragma("unroll") for (int j = 0; j < 4; ++j) \
            acc[i][j] = __builtin_amdgcn_mfma_f32_16x16x32_bf16(aF[i], bF[j], acc[i][j], 0, 0, 0); \
        } while (0)

    STAGE1(aD0, bD0, 0);
    for (int k0 = 0; k0 < DIM; k0 += 64) {
        __syncthreads();
        if (k0 + 32 < DIM) STAGE1(aD1, bD1, k0 + 32);
        COMP1(&Als[0][0], &Bls[0][0]);
        __syncthreads();
        if (k0 + 64 < DIM) STAGE1(aD0, bD0, k0 + 64);
        COMP1(&Als[1][0], &Bls[1][0]);
    }
#undef STAGE1
#undef COMP1

    const int mBase = bm * 128 + wm * 64;
    const int nBase = bn * 128 + wn * 64;
#pragma unroll
    for (int j = 0; j < 4; ++j) {
        const int f = nBase + j * 16 + fr;
        const float bias = b1[e * NF + f];
#pragma unroll
        for (int i = 0; i < 4; ++i) {
            const int m0 = mBase + i * 16 + fq * 4;
#pragma unroll
            for (int r = 0; r < 4; ++r) {
                float v = acc[i][j][r] + bias;
                H[(size_t)(m0 + r) * NF + f] = f2bf(gelu_tanh(v));
            }
        }
    }
}

// ---------- GEMM2: out[token] = gate * (H @ w2 + b2), scattered ----------
// grid (DIM/64, 4, NE); 128x64 tile (2x grid vs 128x128), BK=32, dbuf, swizzled.
__global__ __launch_bounds__(256) void moe_gemm2(const u16* __restrict__ H,
                                                 const u16* __restrict__ W2t,
                                                 const float* __restrict__ b2,
                                                 const int* __restrict__ tos,
                                                 const float* __restrict__ gp,
                                                 float* __restrict__ out) {
    __shared__ alignas(16) u16 Als[2][4096];   // 128 x 32
    __shared__ alignas(16) u16 Bls[2][2048];   // 64 x 32
    const int tid = threadIdx.x, wave = tid >> 6, lane = tid & 63;
    const int e  = blockIdx.z;
    const int bm = e * 4 + blockIdx.y;
    const int bn = blockIdx.x;
    const int r4  = lane >> 2;
    const int gch = (lane & 3) ^ ((lane >> 3) & 3);
    const u16* aS = H + (size_t)(bm * 128 + wave * 32 + r4) * NF + gch * 8;
    const u16* bS = W2t + (size_t)e * DIM * NF
                  + (size_t)(bn * 64 + wave * 16 + r4) * NF + gch * 8;
    u16* aD0 = &Als[0][wave * 1024]; u16* aD1 = &Als[1][wave * 1024];
    u16* bD0 = &Bls[0][wave * 512];  u16* bD1 = &Bls[1][wave * 512];
    f32x4 acc[4][2] = {};
    const int wm = wave & 1, wn = wave >> 1;   // wave grid 2 (M) x 2 (N)
    const int fr = lane & 15, fq = lane >> 4;
    const int rdoff = fr * 32 + (fq ^ ((fr >> 1) & 3)) * 8;

#define STAGE2(AD, BD, K) do { \
        gld16(aS + (K), AD); gld16(aS + (K) + 16 * NF, (AD) + 512); \
        gld16(bS + (K), BD); } while (0)
#define COMP2(AB, BB) do { \
        bf16x8 aF[4], bF[2]; \
        _Pragma("unroll") for (int i = 0; i < 4; ++i) \
            aF[i] = *(const bf16x8*)(const void*)((AB) + (wm * 64 + i * 16) * 32 + rdoff); \
        _Pragma("unroll") for (int j = 0; j < 2; ++j) \
            bF[j] = *(const bf16x8*)(const void*)((BB) + (wn * 32 + j * 16) * 32 + rdoff); \
        _Pragma("unroll") for (int i = 0; i < 4; ++i) \
        _Pragma("unroll") for (int j = 0; j < 2; ++j) \
            acc[i][j] = __builtin_amdgcn_mfma_f32_16x16x32_bf16(aF[i], bF[j], acc[i][j], 0, 0, 0); \
        } while (0)

    STAGE2(aD0, bD0, 0);
    for (int k0 = 0; k0 < NF; k0 += 64) {
        __syncthreads();
        if (k0 + 32 < NF) STAGE2(aD1, bD1, k0 + 32);
        COMP2(&Als[0][0], &Bls[0][0]);
        __syncthreads();
        if (k0 + 64 < NF) STAGE2(aD0, bD0, k0 + 64);
        COMP2(&Als[1][0], &Bls[1][0]);
    }
#undef STAGE2
#undef COMP2

    const int mBase = bm * 128 + wm * 64;
    const int nBase = bn * 64 + wn * 32;
#pragma unroll
    for (int i = 0; i < 4; ++i) {
#pragma unroll
        for (int r = 0; r < 4; ++r) {
            const int m = mBase + i * 16 + fq * 4 + r;
            const int t = tos[m];
            if (t < 0) continue;
            const float g = gp[t];
#pragma unroll
            for (int j = 0; j < 2; ++j) {
                const int d = nBase + j * 16 + fr;
                out[(size_t)t * DIM + d] = g * (acc[i][j][r] + b2[e * DIM + d]);
            }
        }
    }
}

// ---------- launch ----------
extern "C" void kernel_launch(void* const* d_in, const int* in_sizes, int n_in,
                              void* d_out, int out_size, void* d_ws, size_t ws_size,
                              hipStream_t stream) {
    const float* x  = (const float*)d_in[0];
    const float* wg = (const float*)d_in[1];
    const float* w1 = (const float*)d_in[2];
    const float* b1 = (const float*)d_in[3];
    const float* w2 = (const float*)d_in[4];
    const float* b2 = (const float*)d_in[5];
    float* out = (float*)d_out;

    char* ws = (char*)d_ws;
    const size_t WBF_OFF = 0;                                   // 134,217,728 B (shared by w1/w2 bf16)
    const size_t XG_OFF  = WBF_OFF + (size_t)NE * NF * DIM * 2; // 16,777,216 B
    const size_t H_OFF   = XG_OFF + (size_t)TOK * DIM * 2;      // 67,108,864 B
    const size_t SM_OFF  = H_OFF + (size_t)TOK * NF * 2;
    u16* Wbf = (u16*)(ws + WBF_OFF);
    u16* Xg  = (u16*)(ws + XG_OFF);
    u16* H   = (u16*)(ws + H_OFF);
    int*   eidx = (int*)(ws + SM_OFF);                 // 32 KB
    float* gp   = (float*)(ws + SM_OFF + 32768);       // 32 KB
    int*   slot = (int*)(ws + SM_OFF + 65536);         // 32 KB
    int*   tos  = (int*)(ws + SM_OFF + 98304);         // 32 KB
    float* me   = (float*)(ws + SM_OFF + 131072);      // 64 B
    float* wgT  = (float*)(ws + SM_OFF + 131072 + 128);// 64 KB (16B aligned)

    float* tail = out + (size_t)TOK * DIM;             // [l_aux, exp_counts x16]

    moe_init<<<1, 64, 0, stream>>>(me);
    moe_wgT<<<64, 256, 0, stream>>>(wg, wgT);
    moe_gate<<<TOK / 16, 256, 0, stream>>>(x, wgT, eidx, gp, me);
    moe_scan<<<1, 1024, 0, stream>>>(eidx, me, slot, tos, tail);
    moe_gather<<<NE * CAP, 256, 0, stream>>>(x, tos, Xg);
    moe_zero_dropped<<<TOK, 256, 0, stream>>>(slot, out);
    moe_convT<<<NE * (DIM / 64) * (NF / 64), 256, 0, stream>>>(w1, Wbf, DIM, NF);
    moe_gemm1<<<dim3(NF / 128, 4, NE), 256, 0, stream>>>(Xg, Wbf, b1, H);
    moe_convT<<<NE * (NF / 64) * (DIM / 64), 256, 0, stream>>>(w2, Wbf, NF, DIM);
    moe_gemm2<<<dim3(DIM / 64, 4, NE), 256, 0, stream>>>(H, Wbf, b2, tos, gp, out);
}